// Round 8
// baseline (27893.695 us; speedup 1.0000x reference)
//
#include <hip/hip_runtime.h>
#include <hip/hip_bf16.h>

// SNN: B=256, IN=1024, HID=2048, OUT=10, T=100, decay=0.9, thr=1.0, reset=0.
// Layer-pipelined: GEMM1(all t) -> LIF scan -> GEMM2(all t) -> scan -> GEMM3 -> scan.
// fp64 accumulation via v_mfma_f64_16x16x4_f64.
// Ladder: 16rx128c (80.7% MfmaUtil, 2.90ms) -> 32rx64c (85.7%, 2.70ms).
// Round-8: 64 rows x 64 cols per wave (4 rowgroups x 4 col-tiles): 16 MFMAs
// (1024 pipe-cy) per quad-step against the same 4 B-loads -> per-CU B-load
// demand halves again. ~64 AGPR + ~50 VGPR = ~114 <= 128 at (256,4).
// k-chain order per output element unchanged -> absmax bit-identical.

#define B 256
#define IN_DIM 1024
#define HID 2048
#define OUT_DIM 10
#define T_STEPS 100

typedef unsigned long long ull;
typedef double d4 __attribute__((ext_vector_type(4)));

// ---------------- weight fp32 -> fp64 conversion ----------------
__global__ __launch_bounds__(256) void cvt_weights(
    const float* __restrict__ wih, const float* __restrict__ whh,
    const float* __restrict__ who,
    double* __restrict__ Wih, double* __restrict__ Whh, double* __restrict__ Who)
{
    int i = blockIdx.x * 256 + threadIdx.x;
    if (i < IN_DIM * HID) Wih[i] = (double)wih[i];
    if (i < HID * HID)    Whh[i] = (double)whh[i];
    if (i < HID * OUT_DIM) Who[i] = (double)who[i];
}

// ---------------- bit-pack input spikes ----------------
// input_bins layout [B, IN_DIM, T]; produce Xbits[(t*256+b)*16 + i/64] bit i&63.
__global__ __launch_bounds__(256) void bitpack_input(
    const float* __restrict__ inp, ull* __restrict__ Xbits)
{
    int g = blockIdx.x * 4 + (threadIdx.x >> 6);   // 0..4095 waves
    int lane = threadIdx.x & 63;
    int b = g >> 4;          // 0..255
    int ig = g & 15;         // 0..15 (i-group of 64)
    int i = ig * 64 + lane;
    const float* p = inp + ((size_t)b * IN_DIM + i) * T_STEPS;
    for (int t = 0; t < T_STEPS; ++t) {
        ull m = __ballot(p[t] > 0.5f);
        if (lane == 0) Xbits[((size_t)t * B + b) * 16 + ig] = m;
    }
}

// ---------------- MFMA fp64 bit-GEMM (64r x 64c per wave) ----------------
// C[row, n] = sum_k bit(row,k) * W[k, n], k ascending inside each MFMA chain.
// Wave: 4 rowgroups x 4 col-tiles of 16x16. Block = 4 waves = 256 rows.
// Grid: x = rows/256, y = HID/64.
template<int WPR>
__global__ __launch_bounds__(256, 4) void gemm_mfma(
    const ull* __restrict__ bits, int bits_row_off,
    const double* __restrict__ W, double* __restrict__ C)
{
    const int lane = threadIdx.x & 63;
    const int wv = __builtin_amdgcn_readfirstlane(threadIdx.x >> 6);
    const int row0 = blockIdx.x * 256 + wv * 64;  // row base (uniform per wave)
    const int c0 = blockIdx.y * 64;
    const int li = lane & 15;        // A row-in-group / B col / D col
    const int lk = lane >> 4;        // k-within-quad (0..3); D row-group

    d4 acc[4][4];
#pragma unroll
    for (int g = 0; g < 4; ++g)
#pragma unroll
        for (int t = 0; t < 4; ++t) acc[g][t] = (d4){0.0, 0.0, 0.0, 0.0};

    // mask streams: lane li carries rows row0 + g*16 + li (dup across lk)
    const ull* __restrict__ mbase = bits + (size_t)(row0 + bits_row_off + li) * WPR;
    ull mnext[4];
#pragma unroll
    for (int g = 0; g < 4; ++g) mnext[g] = mbase[(size_t)g * 16 * WPR];

    // B fragment pointer: lane loads W[kbase + lk][c0 + t*16 + li]
    const double* __restrict__ wp = W + (size_t)lk * HID + (c0 + li);

    // 2-quad prefetch ring (8 loads in flight, consumed ~2048 pipe-cy later)
    double bq0[4], bq1[4];
#pragma unroll
    for (int t = 0; t < 4; ++t) bq0[t] = wp[t * 16];
    wp += 4 * HID;
#pragma unroll
    for (int t = 0; t < 4; ++t) bq1[t] = wp[t * 16];
    wp += 4 * HID;   // ring overruns past W end by <=2 quads: lands in next ws buffer, safe

#pragma unroll 1
    for (int w = 0; w < WPR; ++w) {
        ull mrot[4];
#pragma unroll
        for (int g = 0; g < 4; ++g) {
            mrot[g] = mnext[g] >> lk;     // per-lane pre-shift by k-within-quad
            mnext[g] = mbase[(size_t)g * 16 * WPR + w + 1];  // 1-word overrun: in-ws, safe
        }
#pragma unroll
        for (int qp = 0; qp < 8; ++qp) {
            {   // even quad: bits qp*8 + lk
                double cur[4];
#pragma unroll
                for (int t = 0; t < 4; ++t) { cur[t] = bq0[t]; bq0[t] = wp[t * 16]; }
                wp += 4 * HID;
#pragma unroll
                for (int g = 0; g < 4; ++g) {
                    double a = (double)((unsigned)(mrot[g] >> (qp * 8)) & 1u);
#pragma unroll
                    for (int t = 0; t < 4; ++t)
                        acc[g][t] = __builtin_amdgcn_mfma_f64_16x16x4f64(a, cur[t], acc[g][t], 0, 0, 0);
                }
            }
            {   // odd quad: bits qp*8 + 4 + lk
                double cur[4];
#pragma unroll
                for (int t = 0; t < 4; ++t) { cur[t] = bq1[t]; bq1[t] = wp[t * 16]; }
                wp += 4 * HID;
#pragma unroll
                for (int g = 0; g < 4; ++g) {
                    double a = (double)((unsigned)(mrot[g] >> (qp * 8 + 4)) & 1u);
#pragma unroll
                    for (int t = 0; t < 4; ++t)
                        acc[g][t] = __builtin_amdgcn_mfma_f64_16x16x4f64(a, cur[t], acc[g][t], 0, 0, 0);
                }
            }
        }
    }

    // D layout: row = g*16 + lk*4 + r, col = t*16 + li
#pragma unroll
    for (int g = 0; g < 4; ++g) {
#pragma unroll
        for (int t = 0; t < 4; ++t) {
#pragma unroll
            for (int r = 0; r < 4; ++r) {
                C[(size_t)(row0 + g * 16 + lk * 4 + r) * HID + c0 + t * 16 + li] = acc[g][t][r];
            }
        }
    }
}

// ---------------- output bit-GEMM: 10 columns (row-lane; small) ----------
__global__ __launch_bounds__(256) void gemm_out(
    const ull* __restrict__ bits, int bits_row_off,
    const double* __restrict__ W, double* __restrict__ C3)
{
    const int lane = threadIdx.x & 63;
    const int wave = threadIdx.x >> 6;
    const int row = blockIdx.x * 256 + wave * 64 + lane;

    double acc[OUT_DIM];
#pragma unroll
    for (int j = 0; j < OUT_DIM; ++j) acc[j] = 0.0;

    const ull* __restrict__ brow = bits + (size_t)(row + bits_row_off) * 32;
    for (int w = 0; w < 32; ++w) {
        ull m = brow[w];
        const double* __restrict__ wk = W + (size_t)(w * 64) * OUT_DIM;
#pragma unroll 4
        for (int kk = 0; kk < 64; ++kk) {
            double bd = (double)(unsigned int)(m & 1ull);
            m >>= 1;
#pragma unroll
            for (int j = 0; j < OUT_DIM; ++j)
                acc[j] = fma(bd, wk[j], acc[j]);
            wk += OUT_DIM;
        }
    }
    double* __restrict__ crow = C3 + (size_t)row * OUT_DIM;
#pragma unroll
    for (int j = 0; j < OUT_DIM; ++j) crow[j] = acc[j];
}

// ---------------- LIF scan for a hidden layer (2048 units) ----------------
__global__ __launch_bounds__(256) void lif_scan(
    const double* __restrict__ C, double* __restrict__ vstate,
    ull* __restrict__ Sbits, int bits_row_off, int Tl, int first)
{
    int g = blockIdx.x * 4 + (threadIdx.x >> 6);  // 0..8191
    int lane = threadIdx.x & 63;
    int b = g >> 5;        // 0..255
    int ng = g & 31;       // 0..31
    int n = ng * 64 + lane;
    double v = first ? 0.0 : vstate[(size_t)b * HID + n];
    for (int tl = 0; tl < Tl; ++tl) {
        double c = C[((size_t)tl * B + b) * HID + n];
        v = v * 0.9 + c;
        bool s = (v >= 1.0);
        if (s) v = 0.0;
        ull mask = __ballot(s);
        if (lane == 0)
            Sbits[((size_t)(bits_row_off + tl * B + b)) * 32 + ng] = mask;
    }
    vstate[(size_t)b * HID + n] = v;
}

// ---------------- output LIF scan + rate accumulation ----------------
__global__ __launch_bounds__(256) void lif_out(
    const double* __restrict__ C3, double* __restrict__ vstate,
    int* __restrict__ cnt_state, float* __restrict__ out, int Tl, int first)
{
    int tid = blockIdx.x * 256 + threadIdx.x;
    if (tid >= B * OUT_DIM) return;
    int b = tid / OUT_DIM, o = tid % OUT_DIM;
    double v = first ? 0.0 : vstate[tid];
    int cnt = first ? 0 : cnt_state[tid];
    for (int tl = 0; tl < Tl; ++tl) {
        double c = C3[((size_t)tl * B + b) * OUT_DIM + o];
        v = v * 0.9 + c;
        if (v >= 1.0) { cnt++; v = 0.0; }
    }
    vstate[tid] = v;
    cnt_state[tid] = cnt;
    out[tid] = (float)((double)cnt / (double)T_STEPS);
}

extern "C" void kernel_launch(void* const* d_in, const int* in_sizes, int n_in,
                              void* d_out, int out_size, void* d_ws, size_t ws_size,
                              hipStream_t stream) {
    const float* inp = (const float*)d_in[0];   // [256,1024,100]
    const float* wih = (const float*)d_in[1];   // [1024,2048]
    const float* whh = (const float*)d_in[2];   // [1,2048,2048]
    const float* who = (const float*)d_in[3];   // [2048,10]
    float* out = (float*)d_out;                 // [256,10]

    // ---- workspace layout ----
    unsigned char* p = (unsigned char*)d_ws;
    auto alloc = [&](size_t sz) -> void* {
        void* r = (void*)p;
        p += (sz + 255) & ~(size_t)255;
        return r;
    };
    double* Wih64 = (double*)alloc((size_t)IN_DIM * HID * 8);      // 16.8 MB
    double* Whh64 = (double*)alloc((size_t)HID * HID * 8);         // 33.6 MB
    double* Who64 = (double*)alloc((size_t)HID * OUT_DIM * 8);
    ull* Xbits = (ull*)alloc((size_t)T_STEPS * B * 16 * 8);        // 3.3 MB
    ull* S1    = (ull*)alloc((size_t)T_STEPS * B * 32 * 8);        // 6.6 MB
    ull* S2    = (ull*)alloc((size_t)T_STEPS * B * 32 * 8);        // 6.6 MB
    double* v1 = (double*)alloc((size_t)B * HID * 8);
    double* v2 = (double*)alloc((size_t)B * HID * 8);
    double* vo = (double*)alloc((size_t)B * OUT_DIM * 8);
    int* cnts  = (int*)alloc((size_t)B * OUT_DIM * 4);

    size_t used = (size_t)(p - (unsigned char*)d_ws);
    size_t remain = (ws_size > used) ? (ws_size - used) : 0;
    size_t per_t = (size_t)B * HID * 8 + (size_t)B * OUT_DIM * 8 + 1024;
    int CH = (int)(remain / per_t);
    if (CH > T_STEPS) CH = T_STEPS;
    if (CH < 1) CH = 1;
    double* C3 = (double*)alloc((size_t)CH * B * OUT_DIM * 8);
    double* C  = (double*)alloc((size_t)CH * B * HID * 8);

    // ---- one-time prep ----
    cvt_weights<<<(HID * HID + 255) / 256, 256, 0, stream>>>(
        wih, whh, who, Wih64, Whh64, Who64);
    bitpack_input<<<(B * (IN_DIM / 64)) / 4, 256, 0, stream>>>(inp, Xbits);

    // ---- chunked time loop ----
    for (int t0 = 0; t0 < T_STEPS; t0 += CH) {
        int L = T_STEPS - t0;
        if (L > CH) L = CH;
        int rows = L * B;            // multiple of 256
        int first = (t0 == 0) ? 1 : 0;

        // layer 1
        gemm_mfma<16><<<dim3(rows / 256, HID / 64), 256, 0, stream>>>(
            Xbits, t0 * B, Wih64, C);
        lif_scan<<<(B * (HID / 64)) / 4, 256, 0, stream>>>(
            C, v1, S1, t0 * B, L, first);

        // layer 2
        gemm_mfma<32><<<dim3(rows / 256, HID / 64), 256, 0, stream>>>(
            S1, t0 * B, Whh64, C);
        lif_scan<<<(B * (HID / 64)) / 4, 256, 0, stream>>>(
            C, v2, S2, t0 * B, L, first);

        // output layer
        gemm_out<<<rows / 256, 256, 0, stream>>>(S2, t0 * B, Who64, C3);
        lif_out<<<(B * OUT_DIM + 255) / 256, 256, 0, stream>>>(
            C3, vo, cnts, out, L, first);
    }
}

// Round 9
// 6143.137 us; speedup vs baseline: 4.5406x; 4.5406x over previous
//
#include <hip/hip_runtime.h>
#include <hip/hip_bf16.h>

// SNN: B=256, IN=1024, HID=2048, OUT=10, T=100, decay=0.9, thr=1.0, reset=0.
// Layer-pipelined: GEMM1(all t) -> LIF scan -> GEMM2(all t) -> scan -> GEMM3 -> scan.
// fp64 accumulation via v_mfma_f64_16x16x4_f64.
// Tile ladder: 16rx128c (80.7% MfmaUtil, 2.90ms) -> 32rx64c (85.7%, 2.70ms)
// -> 64rx64c SPILLED (128 acc regs; 44GB scratch writes, 15% MfmaUtil).
// Round-9: round-7 kernel (32rx64c, the sweet spot) with (256,5): reg cap
// ~96-102 vs 84 used -> codegen preserved, +1 wave/SIMD of latency hiding.
// k-chain order per output element unchanged -> absmax bit-identical.

#define B 256
#define IN_DIM 1024
#define HID 2048
#define OUT_DIM 10
#define T_STEPS 100

typedef unsigned long long ull;
typedef double d4 __attribute__((ext_vector_type(4)));

// ---------------- weight fp32 -> fp64 conversion ----------------
__global__ __launch_bounds__(256) void cvt_weights(
    const float* __restrict__ wih, const float* __restrict__ whh,
    const float* __restrict__ who,
    double* __restrict__ Wih, double* __restrict__ Whh, double* __restrict__ Who)
{
    int i = blockIdx.x * 256 + threadIdx.x;
    if (i < IN_DIM * HID) Wih[i] = (double)wih[i];
    if (i < HID * HID)    Whh[i] = (double)whh[i];
    if (i < HID * OUT_DIM) Who[i] = (double)who[i];
}

// ---------------- bit-pack input spikes ----------------
// input_bins layout [B, IN_DIM, T]; produce Xbits[(t*256+b)*16 + i/64] bit i&63.
__global__ __launch_bounds__(256) void bitpack_input(
    const float* __restrict__ inp, ull* __restrict__ Xbits)
{
    int g = blockIdx.x * 4 + (threadIdx.x >> 6);   // 0..4095 waves
    int lane = threadIdx.x & 63;
    int b = g >> 4;          // 0..255
    int ig = g & 15;         // 0..15 (i-group of 64)
    int i = ig * 64 + lane;
    const float* p = inp + ((size_t)b * IN_DIM + i) * T_STEPS;
    for (int t = 0; t < T_STEPS; ++t) {
        ull m = __ballot(p[t] > 0.5f);
        if (lane == 0) Xbits[((size_t)t * B + b) * 16 + ig] = m;
    }
}

// ---------------- MFMA fp64 bit-GEMM (32r x 64c per wave) ----------------
// C[row, n] = sum_k bit(row,k) * W[k, n], k ascending inside each MFMA chain.
// Wave: 2 rowgroups x 4 col-tiles of 16x16. Block = 4 waves = 128 rows.
// Grid: x = rows/128, y = HID/64.
template<int WPR>
__global__ __launch_bounds__(256, 5) void gemm_mfma(
    const ull* __restrict__ bits, int bits_row_off,
    const double* __restrict__ W, double* __restrict__ C)
{
    const int lane = threadIdx.x & 63;
    const int wv = __builtin_amdgcn_readfirstlane(threadIdx.x >> 6);
    const int row0 = blockIdx.x * 128 + wv * 32;  // row base (uniform per wave)
    const int c0 = blockIdx.y * 64;
    const int li = lane & 15;        // A row-in-group / B col / D col
    const int lk = lane >> 4;        // k-within-quad (0..3); D row-group

    d4 acc[2][4];
#pragma unroll
    for (int g = 0; g < 2; ++g)
#pragma unroll
        for (int t = 0; t < 4; ++t) acc[g][t] = (d4){0.0, 0.0, 0.0, 0.0};

    // mask streams: lane li carries rows row0+li and row0+16+li (dup across lk)
    const ull* __restrict__ mptr0 = bits + (size_t)(row0 + bits_row_off + li) * WPR;
    const ull* __restrict__ mptr1 = mptr0 + (size_t)16 * WPR;
    ull mnext0 = mptr0[0];
    ull mnext1 = mptr1[0];

    // B fragment pointer: lane loads W[kbase + lk][c0 + t*16 + li]
    const double* __restrict__ wp = W + (size_t)lk * HID + (c0 + li);

    // 2-quad prefetch ring (8 loads in flight, consumed ~1024 cy later)
    double bq0[4], bq1[4];
#pragma unroll
    for (int t = 0; t < 4; ++t) bq0[t] = wp[t * 16];
    wp += 4 * HID;
#pragma unroll
    for (int t = 0; t < 4; ++t) bq1[t] = wp[t * 16];
    wp += 4 * HID;   // ring overruns past W end by <=2 quads: lands in next ws buffer, safe

#pragma unroll 1
    for (int w = 0; w < WPR; ++w) {
        ull mvec0 = mnext0, mvec1 = mnext1;
        mnext0 = mptr0[w + 1];            // 1-word overrun at end: in-ws, safe
        mnext1 = mptr1[w + 1];
        ull mrot0 = mvec0 >> lk;          // per-lane pre-shift by k-within-quad
        ull mrot1 = mvec1 >> lk;
#pragma unroll
        for (int qp = 0; qp < 8; ++qp) {
            {   // even quad: bits qp*8 + lk
                double a0 = (double)((unsigned)(mrot0 >> (qp * 8)) & 1u);
                double a1 = (double)((unsigned)(mrot1 >> (qp * 8)) & 1u);
                double cur[4];
#pragma unroll
                for (int t = 0; t < 4; ++t) { cur[t] = bq0[t]; bq0[t] = wp[t * 16]; }
                wp += 4 * HID;
#pragma unroll
                for (int t = 0; t < 4; ++t) {
                    acc[0][t] = __builtin_amdgcn_mfma_f64_16x16x4f64(a0, cur[t], acc[0][t], 0, 0, 0);
                    acc[1][t] = __builtin_amdgcn_mfma_f64_16x16x4f64(a1, cur[t], acc[1][t], 0, 0, 0);
                }
            }
            {   // odd quad: bits qp*8 + 4 + lk
                double a0 = (double)((unsigned)(mrot0 >> (qp * 8 + 4)) & 1u);
                double a1 = (double)((unsigned)(mrot1 >> (qp * 8 + 4)) & 1u);
                double cur[4];
#pragma unroll
                for (int t = 0; t < 4; ++t) { cur[t] = bq1[t]; bq1[t] = wp[t * 16]; }
                wp += 4 * HID;
#pragma unroll
                for (int t = 0; t < 4; ++t) {
                    acc[0][t] = __builtin_amdgcn_mfma_f64_16x16x4f64(a0, cur[t], acc[0][t], 0, 0, 0);
                    acc[1][t] = __builtin_amdgcn_mfma_f64_16x16x4f64(a1, cur[t], acc[1][t], 0, 0, 0);
                }
            }
        }
    }

    // D layout: row = g*16 + lk*4 + r, col = t*16 + li
#pragma unroll
    for (int g = 0; g < 2; ++g) {
#pragma unroll
        for (int t = 0; t < 4; ++t) {
#pragma unroll
            for (int r = 0; r < 4; ++r) {
                C[(size_t)(row0 + g * 16 + lk * 4 + r) * HID + c0 + t * 16 + li] = acc[g][t][r];
            }
        }
    }
}

// ---------------- output bit-GEMM: 10 columns (row-lane; small) ----------
__global__ __launch_bounds__(256) void gemm_out(
    const ull* __restrict__ bits, int bits_row_off,
    const double* __restrict__ W, double* __restrict__ C3)
{
    const int lane = threadIdx.x & 63;
    const int wave = threadIdx.x >> 6;
    const int row = blockIdx.x * 256 + wave * 64 + lane;

    double acc[OUT_DIM];
#pragma unroll
    for (int j = 0; j < OUT_DIM; ++j) acc[j] = 0.0;

    const ull* __restrict__ brow = bits + (size_t)(row + bits_row_off) * 32;
    for (int w = 0; w < 32; ++w) {
        ull m = brow[w];
        const double* __restrict__ wk = W + (size_t)(w * 64) * OUT_DIM;
#pragma unroll 4
        for (int kk = 0; kk < 64; ++kk) {
            double bd = (double)(unsigned int)(m & 1ull);
            m >>= 1;
#pragma unroll
            for (int j = 0; j < OUT_DIM; ++j)
                acc[j] = fma(bd, wk[j], acc[j]);
            wk += OUT_DIM;
        }
    }
    double* __restrict__ crow = C3 + (size_t)row * OUT_DIM;
#pragma unroll
    for (int j = 0; j < OUT_DIM; ++j) crow[j] = acc[j];
}

// ---------------- LIF scan for a hidden layer (2048 units) ----------------
__global__ __launch_bounds__(256) void lif_scan(
    const double* __restrict__ C, double* __restrict__ vstate,
    ull* __restrict__ Sbits, int bits_row_off, int Tl, int first)
{
    int g = blockIdx.x * 4 + (threadIdx.x >> 6);  // 0..8191
    int lane = threadIdx.x & 63;
    int b = g >> 5;        // 0..255
    int ng = g & 31;       // 0..31
    int n = ng * 64 + lane;
    double v = first ? 0.0 : vstate[(size_t)b * HID + n];
    for (int tl = 0; tl < Tl; ++tl) {
        double c = C[((size_t)tl * B + b) * HID + n];
        v = v * 0.9 + c;
        bool s = (v >= 1.0);
        if (s) v = 0.0;
        ull mask = __ballot(s);
        if (lane == 0)
            Sbits[((size_t)(bits_row_off + tl * B + b)) * 32 + ng] = mask;
    }
    vstate[(size_t)b * HID + n] = v;
}

// ---------------- output LIF scan + rate accumulation ----------------
__global__ __launch_bounds__(256) void lif_out(
    const double* __restrict__ C3, double* __restrict__ vstate,
    int* __restrict__ cnt_state, float* __restrict__ out, int Tl, int first)
{
    int tid = blockIdx.x * 256 + threadIdx.x;
    if (tid >= B * OUT_DIM) return;
    int b = tid / OUT_DIM, o = tid % OUT_DIM;
    double v = first ? 0.0 : vstate[tid];
    int cnt = first ? 0 : cnt_state[tid];
    for (int tl = 0; tl < Tl; ++tl) {
        double c = C3[((size_t)tl * B + b) * OUT_DIM + o];
        v = v * 0.9 + c;
        if (v >= 1.0) { cnt++; v = 0.0; }
    }
    vstate[tid] = v;
    cnt_state[tid] = cnt;
    out[tid] = (float)((double)cnt / (double)T_STEPS);
}

extern "C" void kernel_launch(void* const* d_in, const int* in_sizes, int n_in,
                              void* d_out, int out_size, void* d_ws, size_t ws_size,
                              hipStream_t stream) {
    const float* inp = (const float*)d_in[0];   // [256,1024,100]
    const float* wih = (const float*)d_in[1];   // [1024,2048]
    const float* whh = (const float*)d_in[2];   // [1,2048,2048]
    const float* who = (const float*)d_in[3];   // [2048,10]
    float* out = (float*)d_out;                 // [256,10]

    // ---- workspace layout ----
    unsigned char* p = (unsigned char*)d_ws;
    auto alloc = [&](size_t sz) -> void* {
        void* r = (void*)p;
        p += (sz + 255) & ~(size_t)255;
        return r;
    };
    double* Wih64 = (double*)alloc((size_t)IN_DIM * HID * 8);      // 16.8 MB
    double* Whh64 = (double*)alloc((size_t)HID * HID * 8);         // 33.6 MB
    double* Who64 = (double*)alloc((size_t)HID * OUT_DIM * 8);
    ull* Xbits = (ull*)alloc((size_t)T_STEPS * B * 16 * 8);        // 3.3 MB
    ull* S1    = (ull*)alloc((size_t)T_STEPS * B * 32 * 8);        // 6.6 MB
    ull* S2    = (ull*)alloc((size_t)T_STEPS * B * 32 * 8);        // 6.6 MB
    double* v1 = (double*)alloc((size_t)B * HID * 8);
    double* v2 = (double*)alloc((size_t)B * HID * 8);
    double* vo = (double*)alloc((size_t)B * OUT_DIM * 8);
    int* cnts  = (int*)alloc((size_t)B * OUT_DIM * 4);

    size_t used = (size_t)(p - (unsigned char*)d_ws);
    size_t remain = (ws_size > used) ? (ws_size - used) : 0;
    size_t per_t = (size_t)B * HID * 8 + (size_t)B * OUT_DIM * 8 + 1024;
    int CH = (int)(remain / per_t);
    if (CH > T_STEPS) CH = T_STEPS;
    if (CH < 1) CH = 1;
    double* C3 = (double*)alloc((size_t)CH * B * OUT_DIM * 8);
    double* C  = (double*)alloc((size_t)CH * B * HID * 8);

    // ---- one-time prep ----
    cvt_weights<<<(HID * HID + 255) / 256, 256, 0, stream>>>(
        wih, whh, who, Wih64, Whh64, Who64);
    bitpack_input<<<(B * (IN_DIM / 64)) / 4, 256, 0, stream>>>(inp, Xbits);

    // ---- chunked time loop ----
    for (int t0 = 0; t0 < T_STEPS; t0 += CH) {
        int L = T_STEPS - t0;
        if (L > CH) L = CH;
        int rows = L * B;            // multiple of 128
        int first = (t0 == 0) ? 1 : 0;

        // layer 1
        gemm_mfma<16><<<dim3(rows / 128, HID / 64), 256, 0, stream>>>(
            Xbits, t0 * B, Wih64, C);
        lif_scan<<<(B * (HID / 64)) / 4, 256, 0, stream>>>(
            C, v1, S1, t0 * B, L, first);

        // layer 2
        gemm_mfma<32><<<dim3(rows / 128, HID / 64), 256, 0, stream>>>(
            S1, t0 * B, Whh64, C);
        lif_scan<<<(B * (HID / 64)) / 4, 256, 0, stream>>>(
            C, v2, S2, t0 * B, L, first);

        // output layer
        gemm_out<<<rows / 256, 256, 0, stream>>>(S2, t0 * B, Who64, C3);
        lif_out<<<(B * OUT_DIM + 255) / 256, 256, 0, stream>>>(
            C3, vo, cnts, out, L, first);
    }
}

// Round 10
// 5023.784 us; speedup vs baseline: 5.5523x; 1.2228x over previous
//
#include <hip/hip_runtime.h>
#include <hip/hip_bf16.h>

// SNN: B=256, IN=1024, HID=2048, OUT=10, T=100, decay=0.9, thr=1.0, reset=0.
// Layer-pipelined: GEMM1(all t) -> LIF scan -> GEMM2(all t) -> scan -> GEMM3 -> scan.
// Round-10: hidden-layer GEMMs moved to the i8 matrix pipe (Ozaki-style split):
//   w ≈ 2^-39 * sum_{c=0}^{4} q_c * 256^c   (signed-byte digits, exact for |w|>=2^-17)
//   current = (double)(sum_c S_c << 8c) * 2^-39, S_c = i32 MFMA accumulators (EXACT ints)
// A = spike bits as i8 0/1 (exact). Integer accumulation has no rounding/order issues;
// currents become exact sums -> same one-flip error class as the passing fp64 rounds.
// LIF scans / gemm_out (fp64) / bitpack unchanged from the proven round-7 kernel.

#define B 256
#define IN_DIM 1024
#define HID 2048
#define OUT_DIM 10
#define T_STEPS 100
#define NCH 5

typedef unsigned long long ull;
typedef int v4i __attribute__((ext_vector_type(4)));

// ---- weight fp32 -> 5 signed base-256 digit planes of round(w*2^39), layout [c][n][k] ----
template<int K>
__global__ __launch_bounds__(256) void cvt_w_i8(
    const float* __restrict__ W, signed char* __restrict__ Bq)
{
    size_t id = (size_t)blockIdx.x * 256 + threadIdx.x;
    if (id >= (size_t)K * HID) return;
    int k = (int)(id % (size_t)K);
    int n = (int)(id / (size_t)K);
    double w = (double)W[(size_t)k * HID + n];
    long long V = __double2ll_rn(w * 549755813888.0);  // w * 2^39, exact-rounded
#pragma unroll
    for (int c = 0; c < 4; ++c) {
        int r = (int)(signed char)(V & 0xFF);          // balanced digit in [-128,127]
        Bq[((size_t)c * HID + n) * K + k] = (signed char)r;
        V = (V - r) >> 8;
    }
    Bq[((size_t)4 * HID + n) * K + k] = (signed char)V; // |V| <= ~90 for |w|<=1
}

// ---- output weights fp32 -> fp64 (gemm_out stays fp64) ----
__global__ __launch_bounds__(256) void cvt_who(
    const float* __restrict__ who, double* __restrict__ Who64)
{
    int i = blockIdx.x * 256 + threadIdx.x;
    if (i < HID * OUT_DIM) Who64[i] = (double)who[i];
}

// ---- bit-pack input spikes: [B, IN_DIM, T] -> Xbits[(t*256+b)*16 + i/64] bit i&63 ----
__global__ __launch_bounds__(256) void bitpack_input(
    const float* __restrict__ inp, ull* __restrict__ Xbits)
{
    int g = blockIdx.x * 4 + (threadIdx.x >> 6);   // 0..4095 waves
    int lane = threadIdx.x & 63;
    int b = g >> 4;
    int ig = g & 15;
    int i = ig * 64 + lane;
    const float* p = inp + ((size_t)b * IN_DIM + i) * T_STEPS;
    for (int t = 0; t < T_STEPS; ++t) {
        ull m = __ballot(p[t] > 0.5f);
        if (lane == 0) Xbits[((size_t)t * B + b) * 16 + ig] = m;
    }
}

// ---- i8 Ozaki bit-GEMM: C[row,n] = exact sum_k bit(row,k)*w[k,n] ----
// Wave: 32 rows x 16 cols; 2 row-tiles of 16x16x64 MFMA x 5 digit chunks.
// Block = 4 waves = 128 rows. Grid: x = rows/128, y = HID/16.
// A: m=lane&15, k=(lane>>4)*16+j (bytes of 4 dwords). B: n=lane&15, same k.
// D: col=lane&15, row=(lane>>4)*4+reg (dtype-independent, HW-verified family).
template<int K>
__global__ __launch_bounds__(256, 3) void gemm_i8(
    const ull* __restrict__ bits, int bits_row_off,
    const signed char* __restrict__ Bq, double* __restrict__ C)
{
    constexpr int WPR = K / 64;
    const int lane = threadIdx.x & 63;
    const int wv = __builtin_amdgcn_readfirstlane(threadIdx.x >> 6);
    const int row0 = blockIdx.x * 128 + wv * 32;
    const int c0 = blockIdx.y * 16;
    const int li = lane & 15;
    const int lk = lane >> 4;
    const int sh = lk * 16;

    v4i acc[2][NCH];
#pragma unroll
    for (int g = 0; g < 2; ++g)
#pragma unroll
        for (int c = 0; c < NCH; ++c) acc[g][c] = (v4i){0, 0, 0, 0};

    // mask streams: lane li carries rows row0+li and row0+16+li (dup across lk)
    const ull* __restrict__ mptr0 = bits + (size_t)(row0 + bits_row_off + li) * WPR;
    const ull* __restrict__ mptr1 = mptr0 + (size_t)16 * WPR;

    // B fragment base: digit plane c, col n=c0+li, k-window lk*16
    const signed char* __restrict__ bp = Bq + (size_t)(c0 + li) * K + sh;
    const size_t cs = (size_t)HID * K;   // plane stride

    ull mn0 = mptr0[0], mn1 = mptr1[0];
    v4i bn[NCH];
#pragma unroll
    for (int c = 0; c < NCH; ++c) bn[c] = *(const v4i*)(bp + c * cs);

#pragma unroll 1
    for (int w = 0; w < WPR; ++w) {
        ull m0 = mn0, m1 = mn1;
        mn0 = mptr0[w + 1];              // 1-word overrun at end: in-ws, safe
        mn1 = mptr1[w + 1];
        v4i bc[NCH];
#pragma unroll
        for (int c = 0; c < NCH; ++c) {
            bc[c] = bn[c];
            bn[c] = *(const v4i*)(bp + c * cs + (size_t)(w + 1) * 64);  // <=64B overrun: safe
        }
        unsigned s0 = (unsigned)(m0 >> sh) & 0xFFFFu;
        unsigned s1 = (unsigned)(m1 >> sh) & 0xFFFFu;
        v4i a0, a1;
#pragma unroll
        for (int d = 0; d < 4; ++d) {
            unsigned t0 = s0 >> (4 * d), t1 = s1 >> (4 * d);
            a0[d] = (int)((t0 & 1u) | ((t0 & 2u) << 7) | ((t0 & 4u) << 14) | ((t0 & 8u) << 21));
            a1[d] = (int)((t1 & 1u) | ((t1 & 2u) << 7) | ((t1 & 4u) << 14) | ((t1 & 8u) << 21));
        }
#pragma unroll
        for (int c = 0; c < NCH; ++c) {
            acc[0][c] = __builtin_amdgcn_mfma_i32_16x16x64_i8(a0, bc[c], acc[0][c], 0, 0, 0);
            acc[1][c] = __builtin_amdgcn_mfma_i32_16x16x64_i8(a1, bc[c], acc[1][c], 0, 0, 0);
        }
    }

    // exact recombination: V = ((((S4<<8)+S3)<<8+S2)<<8+S1)<<8+S0; |V| < 2^51
#pragma unroll
    for (int g = 0; g < 2; ++g) {
#pragma unroll
        for (int r = 0; r < 4; ++r) {
            long long V = (long long)acc[g][4][r];
            V = (V << 8) + (long long)acc[g][3][r];
            V = (V << 8) + (long long)acc[g][2][r];
            V = (V << 8) + (long long)acc[g][1][r];
            V = (V << 8) + (long long)acc[g][0][r];
            C[(size_t)(row0 + g * 16 + lk * 4 + r) * HID + c0 + li] =
                (double)V * 0x1p-39;
        }
    }
}

// ---- output bit-GEMM: 10 columns (row-lane; fp64, unchanged) ----
__global__ __launch_bounds__(256) void gemm_out(
    const ull* __restrict__ bits, int bits_row_off,
    const double* __restrict__ W, double* __restrict__ C3)
{
    const int lane = threadIdx.x & 63;
    const int wave = threadIdx.x >> 6;
    const int row = blockIdx.x * 256 + wave * 64 + lane;

    double acc[OUT_DIM];
#pragma unroll
    for (int j = 0; j < OUT_DIM; ++j) acc[j] = 0.0;

    const ull* __restrict__ brow = bits + (size_t)(row + bits_row_off) * 32;
    for (int w = 0; w < 32; ++w) {
        ull m = brow[w];
        const double* __restrict__ wk = W + (size_t)(w * 64) * OUT_DIM;
#pragma unroll 4
        for (int kk = 0; kk < 64; ++kk) {
            double bd = (double)(unsigned int)(m & 1ull);
            m >>= 1;
#pragma unroll
            for (int j = 0; j < OUT_DIM; ++j)
                acc[j] = fma(bd, wk[j], acc[j]);
            wk += OUT_DIM;
        }
    }
    double* __restrict__ crow = C3 + (size_t)row * OUT_DIM;
#pragma unroll
    for (int j = 0; j < OUT_DIM; ++j) crow[j] = acc[j];
}

// ---- LIF scan for a hidden layer (2048 units), fp64, unchanged ----
__global__ __launch_bounds__(256) void lif_scan(
    const double* __restrict__ C, double* __restrict__ vstate,
    ull* __restrict__ Sbits, int bits_row_off, int Tl, int first)
{
    int g = blockIdx.x * 4 + (threadIdx.x >> 6);
    int lane = threadIdx.x & 63;
    int b = g >> 5;
    int ng = g & 31;
    int n = ng * 64 + lane;
    double v = first ? 0.0 : vstate[(size_t)b * HID + n];
    for (int tl = 0; tl < Tl; ++tl) {
        double c = C[((size_t)tl * B + b) * HID + n];
        v = v * 0.9 + c;
        bool s = (v >= 1.0);
        if (s) v = 0.0;
        ull mask = __ballot(s);
        if (lane == 0)
            Sbits[((size_t)(bits_row_off + tl * B + b)) * 32 + ng] = mask;
    }
    vstate[(size_t)b * HID + n] = v;
}

// ---- output LIF scan + rate accumulation, unchanged ----
__global__ __launch_bounds__(256) void lif_out(
    const double* __restrict__ C3, double* __restrict__ vstate,
    int* __restrict__ cnt_state, float* __restrict__ out, int Tl, int first)
{
    int tid = blockIdx.x * 256 + threadIdx.x;
    if (tid >= B * OUT_DIM) return;
    int b = tid / OUT_DIM, o = tid % OUT_DIM;
    double v = first ? 0.0 : vstate[tid];
    int cnt = first ? 0 : cnt_state[tid];
    for (int tl = 0; tl < Tl; ++tl) {
        double c = C3[((size_t)tl * B + b) * OUT_DIM + o];
        v = v * 0.9 + c;
        if (v >= 1.0) { cnt++; v = 0.0; }
    }
    vstate[tid] = v;
    cnt_state[tid] = cnt;
    out[tid] = (float)((double)cnt / (double)T_STEPS);
}

extern "C" void kernel_launch(void* const* d_in, const int* in_sizes, int n_in,
                              void* d_out, int out_size, void* d_ws, size_t ws_size,
                              hipStream_t stream) {
    const float* inp = (const float*)d_in[0];   // [256,1024,100]
    const float* wih = (const float*)d_in[1];   // [1024,2048]
    const float* whh = (const float*)d_in[2];   // [1,2048,2048]
    const float* who = (const float*)d_in[3];   // [2048,10]
    float* out = (float*)d_out;                 // [256,10]

    // ---- workspace layout ----
    unsigned char* p = (unsigned char*)d_ws;
    auto alloc = [&](size_t sz) -> void* {
        void* r = (void*)p;
        p += (sz + 255) & ~(size_t)255;
        return r;
    };
    signed char* Bq1 = (signed char*)alloc((size_t)NCH * HID * IN_DIM + 256); // 10.5 MB
    signed char* Bq2 = (signed char*)alloc((size_t)NCH * HID * HID + 256);    // 21 MB
    double* Who64 = (double*)alloc((size_t)HID * OUT_DIM * 8);
    ull* Xbits = (ull*)alloc((size_t)T_STEPS * B * 16 * 8);        // 3.3 MB
    ull* S1    = (ull*)alloc((size_t)T_STEPS * B * 32 * 8);        // 6.6 MB
    ull* S2    = (ull*)alloc((size_t)T_STEPS * B * 32 * 8);        // 6.6 MB
    double* v1 = (double*)alloc((size_t)B * HID * 8);
    double* v2 = (double*)alloc((size_t)B * HID * 8);
    double* vo = (double*)alloc((size_t)B * OUT_DIM * 8);
    int* cnts  = (int*)alloc((size_t)B * OUT_DIM * 4);

    size_t used = (size_t)(p - (unsigned char*)d_ws);
    size_t remain = (ws_size > used) ? (ws_size - used) : 0;
    size_t per_t = (size_t)B * HID * 8 + (size_t)B * OUT_DIM * 8 + 1024;
    int CH = (int)(remain / per_t);
    if (CH > T_STEPS) CH = T_STEPS;
    if (CH < 1) CH = 1;
    double* C3 = (double*)alloc((size_t)CH * B * OUT_DIM * 8);
    double* C  = (double*)alloc((size_t)CH * B * HID * 8);

    // ---- one-time prep ----
    cvt_w_i8<IN_DIM><<<(IN_DIM * HID + 255) / 256, 256, 0, stream>>>(wih, Bq1);
    cvt_w_i8<HID><<<(HID * HID + 255) / 256, 256, 0, stream>>>(whh, Bq2);
    cvt_who<<<(HID * OUT_DIM + 255) / 256, 256, 0, stream>>>(who, Who64);
    bitpack_input<<<(B * (IN_DIM / 64)) / 4, 256, 0, stream>>>(inp, Xbits);

    // ---- chunked time loop ----
    for (int t0 = 0; t0 < T_STEPS; t0 += CH) {
        int L = T_STEPS - t0;
        if (L > CH) L = CH;
        int rows = L * B;            // multiple of 256
        int first = (t0 == 0) ? 1 : 0;

        // layer 1
        gemm_i8<IN_DIM><<<dim3(rows / 128, HID / 16), 256, 0, stream>>>(
            Xbits, t0 * B, Bq1, C);
        lif_scan<<<(B * (HID / 64)) / 4, 256, 0, stream>>>(
            C, v1, S1, t0 * B, L, first);

        // layer 2
        gemm_i8<HID><<<dim3(rows / 128, HID / 16), 256, 0, stream>>>(
            S1, t0 * B, Bq2, C);
        lif_scan<<<(B * (HID / 64)) / 4, 256, 0, stream>>>(
            C, v2, S2, t0 * B, L, first);

        // output layer
        gemm_out<<<rows / 256, 256, 0, stream>>>(S2, t0 * B, Who64, C3);
        lif_out<<<(B * OUT_DIM + 255) / 256, 256, 0, stream>>>(
            C3, vo, cnts, out, L, first);
    }
}

// Round 12
// 2258.340 us; speedup vs baseline: 12.3514x; 2.2245x over previous
//
#include <hip/hip_runtime.h>
#include <hip/hip_bf16.h>

// SNN: B=256, IN=1024, HID=2048, OUT=10, T=100, decay=0.9, thr=1.0, reset=0.
// Layer-pipelined: GEMM1(all t) -> LIF scan -> GEMM2(all t) -> scan -> GEMM3 -> scan.
// Hidden GEMMs: i8 Ozaki split (w = 2^-39 * sum_c q_c 256^c, exact for |w|>=2^-17),
// i32 MFMA accumulation is exact -> currents are exact sums (absmax 0.01025391).
// Round-12: round-11 LDS-staged kernel with the C-store fix: round-11 dropped
// the wave row offset r0l in the epilogue (all waves wrote rows 0..31 of the
// block; rows 32..127 stale -> absmax 0.73). Store now row0 + r0l + g*16+...
//  - masks: whole 128-row panel staged to LDS once (padded stride WPR+1).
//  - B digit planes: pre-swizzled fragment-contiguous 10KB/(colblock,w) regions,
//    double-buffered through LDS (one coop copy + one barrier per 64-k iter).
//  - wave tile 32 rows x 32 cols (acc [2][2][5] v4i = 80 regs), block 128r x 32c.

#define B 256
#define IN_DIM 1024
#define HID 2048
#define OUT_DIM 10
#define T_STEPS 100
#define NCH 5

typedef unsigned long long ull;
typedef int v4i __attribute__((ext_vector_type(4)));

// ---- weight fp32 -> 5 signed base-256 digit planes of round(w*2^39),
// swizzled to MFMA-fragment order: region per (nb32, w) = 10*1024 B, fragment
// (c,ct) at offset (c*2+ct)*1024, byte lane*16+jj where lane=lk*16+li,
// n = nb32*32 + ct*16 + li, k = w*64 + lk*16 + jj. ----
template<int K>
__global__ __launch_bounds__(256) void cvt_w_i8(
    const float* __restrict__ W, signed char* __restrict__ Bq)
{
    constexpr int WPR = K / 64;
    size_t id = (size_t)blockIdx.x * 256 + threadIdx.x;
    if (id >= (size_t)K * HID) return;
    int k = (int)(id % (size_t)K);
    int n = (int)(id / (size_t)K);
    double w = (double)W[(size_t)k * HID + n];
    long long V = __double2ll_rn(w * 549755813888.0);  // w * 2^39
    int wb = k >> 6, lk = (k >> 4) & 3, jj = k & 15;
    int nb32 = n >> 5, ct = (n >> 4) & 1, li = n & 15;
    int lane = lk * 16 + li;
    size_t base = ((size_t)nb32 * WPR + wb) * 10240 + (size_t)lane * 16 + jj;
#pragma unroll
    for (int c = 0; c < 4; ++c) {
        int r = (int)(signed char)(V & 0xFF);          // balanced digit [-128,127]
        Bq[base + (size_t)(c * 2 + ct) * 1024] = (signed char)r;
        V = (V - r) >> 8;
    }
    Bq[base + (size_t)(8 + ct) * 1024] = (signed char)V;
}

// ---- output weights fp32 -> fp64 (gemm_out stays fp64) ----
__global__ __launch_bounds__(256) void cvt_who(
    const float* __restrict__ who, double* __restrict__ Who64)
{
    int i = blockIdx.x * 256 + threadIdx.x;
    if (i < HID * OUT_DIM) Who64[i] = (double)who[i];
}

// ---- bit-pack input spikes: [B, IN_DIM, T] -> Xbits[(t*256+b)*16 + i/64] ----
__global__ __launch_bounds__(256) void bitpack_input(
    const float* __restrict__ inp, ull* __restrict__ Xbits)
{
    int g = blockIdx.x * 4 + (threadIdx.x >> 6);
    int lane = threadIdx.x & 63;
    int b = g >> 4;
    int ig = g & 15;
    int i = ig * 64 + lane;
    const float* p = inp + ((size_t)b * IN_DIM + i) * T_STEPS;
    for (int t = 0; t < T_STEPS; ++t) {
        ull m = __ballot(p[t] > 0.5f);
        if (lane == 0) Xbits[((size_t)t * B + b) * 16 + ig] = m;
    }
}

// ---- i8 Ozaki bit-GEMM, LDS-staged operands ----
// Block: 128 rows x 32 cols, 4 waves (wave = 32 rows x 32 cols).
// Grid: x = rows/128, y = HID/32.
template<int K>
__global__ __launch_bounds__(256, 3) void gemm_i8(
    const ull* __restrict__ bits, int bits_row_off,
    const signed char* __restrict__ Bq, double* __restrict__ C)
{
    constexpr int WPR = K / 64;
    __shared__ ull mlds[128 * (WPR + 1)];
    __shared__ __align__(16) signed char blds[2][10240];

    const int tid = threadIdx.x;
    const int lane = tid & 63;
    const int wv = __builtin_amdgcn_readfirstlane(tid >> 6);
    const int row0 = blockIdx.x * 128;
    const int c0 = blockIdx.y * 32;
    const int li = lane & 15;
    const int lk = lane >> 4;
    const int sh = lk * 16;
    const int r0l = wv * 32;

    // phase 0: mask panel -> LDS (row-major, padded stride WPR+1)
    {
        size_t g0 = (size_t)(row0 + bits_row_off) * WPR;
        for (int idx = tid; idx < 128 * WPR; idx += 256) {
            int r = idx / WPR, w = idx & (WPR - 1);
            mlds[r * (WPR + 1) + w] = bits[g0 + idx];
        }
    }
    // phase 0: B(w=0) -> blds[0]
    const signed char* __restrict__ bsrc = Bq + (size_t)blockIdx.y * WPR * 10240;
    for (int u = tid; u < 640; u += 256)
        *(v4i*)(&blds[0][u * 16]) = *(const v4i*)(bsrc + (size_t)u * 16);
    __syncthreads();

    v4i acc[2][2][NCH];
#pragma unroll
    for (int g = 0; g < 2; ++g)
#pragma unroll
        for (int t = 0; t < 2; ++t)
#pragma unroll
            for (int c = 0; c < NCH; ++c) acc[g][t][c] = (v4i){0, 0, 0, 0};

    int buf = 0;
#pragma unroll 1
    for (int w = 0; w < WPR; ++w) {
        // issue next-iter staging loads early (global -> regs)
        v4i st0, st1, st2;
        const bool more = (w + 1 < WPR);
        const signed char* src = bsrc + (size_t)(w + 1) * 10240;
        if (more) {
            st0 = *(const v4i*)(src + (size_t)tid * 16);
            st1 = *(const v4i*)(src + (size_t)(tid + 256) * 16);
            if (tid < 128) st2 = *(const v4i*)(src + (size_t)(tid + 512) * 16);
        }

        // masks from LDS; build A fragments (bit -> byte via mul-spread)
        ull m0 = mlds[(r0l + li) * (WPR + 1) + w];
        ull m1 = mlds[(r0l + 16 + li) * (WPR + 1) + w];
        unsigned s0 = (unsigned)(m0 >> sh) & 0xFFFFu;
        unsigned s1 = (unsigned)(m1 >> sh) & 0xFFFFu;
        v4i a0, a1;
#pragma unroll
        for (int d = 0; d < 4; ++d) {
            a0[d] = (int)((((s0 >> (4 * d)) & 0xFu) * 0x00204081u) & 0x01010101u);
            a1[d] = (int)((((s1 >> (4 * d)) & 0xFu) * 0x00204081u) & 0x01010101u);
        }

#pragma unroll
        for (int c = 0; c < NCH; ++c) {
#pragma unroll
            for (int t = 0; t < 2; ++t) {
                v4i b = *(const v4i*)(&blds[buf][(c * 2 + t) * 1024 + lane * 16]);
                acc[0][t][c] = __builtin_amdgcn_mfma_i32_16x16x64_i8(a0, b, acc[0][t][c], 0, 0, 0);
                acc[1][t][c] = __builtin_amdgcn_mfma_i32_16x16x64_i8(a1, b, acc[1][t][c], 0, 0, 0);
            }
        }

        // commit staged B to the other buffer, then barrier
        if (more) {
            *(v4i*)(&blds[buf ^ 1][tid * 16]) = st0;
            *(v4i*)(&blds[buf ^ 1][(tid + 256) * 16]) = st1;
            if (tid < 128) *(v4i*)(&blds[buf ^ 1][(tid + 512) * 16]) = st2;
        }
        __syncthreads();
        buf ^= 1;
    }

    // exact recombination: V = ((((S4<<8)+S3)<<8+S2)<<8+S1)<<8+S0; |V| < 2^51
    // D row = r0l + g*16 + lk*4 + r  (r0l: the round-11 missing term)
#pragma unroll
    for (int g = 0; g < 2; ++g) {
#pragma unroll
        for (int t = 0; t < 2; ++t) {
#pragma unroll
            for (int r = 0; r < 4; ++r) {
                long long V = (long long)acc[g][t][4][r];
                V = (V << 8) + (long long)acc[g][t][3][r];
                V = (V << 8) + (long long)acc[g][t][2][r];
                V = (V << 8) + (long long)acc[g][t][1][r];
                V = (V << 8) + (long long)acc[g][t][0][r];
                C[(size_t)(row0 + r0l + g * 16 + lk * 4 + r) * HID + c0 + t * 16 + li] =
                    (double)V * 0x1p-39;
            }
        }
    }
}

// ---- output bit-GEMM: 10 columns (row-lane; fp64, unchanged) ----
__global__ __launch_bounds__(256) void gemm_out(
    const ull* __restrict__ bits, int bits_row_off,
    const double* __restrict__ W, double* __restrict__ C3)
{
    const int lane = threadIdx.x & 63;
    const int wave = threadIdx.x >> 6;
    const int row = blockIdx.x * 256 + wave * 64 + lane;

    double acc[OUT_DIM];
#pragma unroll
    for (int j = 0; j < OUT_DIM; ++j) acc[j] = 0.0;

    const ull* __restrict__ brow = bits + (size_t)(row + bits_row_off) * 32;
    for (int w = 0; w < 32; ++w) {
        ull m = brow[w];
        const double* __restrict__ wk = W + (size_t)(w * 64) * OUT_DIM;
#pragma unroll 4
        for (int kk = 0; kk < 64; ++kk) {
            double bd = (double)(unsigned int)(m & 1ull);
            m >>= 1;
#pragma unroll
            for (int j = 0; j < OUT_DIM; ++j)
                acc[j] = fma(bd, wk[j], acc[j]);
            wk += OUT_DIM;
        }
    }
    double* __restrict__ crow = C3 + (size_t)row * OUT_DIM;
#pragma unroll
    for (int j = 0; j < OUT_DIM; ++j) crow[j] = acc[j];
}

// ---- LIF scan for a hidden layer (2048 units), fp64, unchanged ----
__global__ __launch_bounds__(256) void lif_scan(
    const double* __restrict__ C, double* __restrict__ vstate,
    ull* __restrict__ Sbits, int bits_row_off, int Tl, int first)
{
    int g = blockIdx.x * 4 + (threadIdx.x >> 6);
    int lane = threadIdx.x & 63;
    int b = g >> 5;
    int ng = g & 31;
    int n = ng * 64 + lane;
    double v = first ? 0.0 : vstate[(size_t)b * HID + n];
    for (int tl = 0; tl < Tl; ++tl) {
        double c = C[((size_t)tl * B + b) * HID + n];
        v = v * 0.9 + c;
        bool s = (v >= 1.0);
        if (s) v = 0.0;
        ull mask = __ballot(s);
        if (lane == 0)
            Sbits[((size_t)(bits_row_off + tl * B + b)) * 32 + ng] = mask;
    }
    vstate[(size_t)b * HID + n] = v;
}

// ---- output LIF scan + rate accumulation, unchanged ----
__global__ __launch_bounds__(256) void lif_out(
    const double* __restrict__ C3, double* __restrict__ vstate,
    int* __restrict__ cnt_state, float* __restrict__ out, int Tl, int first)
{
    int tid = blockIdx.x * 256 + threadIdx.x;
    if (tid >= B * OUT_DIM) return;
    int b = tid / OUT_DIM, o = tid % OUT_DIM;
    double v = first ? 0.0 : vstate[tid];
    int cnt = first ? 0 : cnt_state[tid];
    for (int tl = 0; tl < Tl; ++tl) {
        double c = C3[((size_t)tl * B + b) * OUT_DIM + o];
        v = v * 0.9 + c;
        if (v >= 1.0) { cnt++; v = 0.0; }
    }
    vstate[tid] = v;
    cnt_state[tid] = cnt;
    out[tid] = (float)((double)cnt / (double)T_STEPS);
}

extern "C" void kernel_launch(void* const* d_in, const int* in_sizes, int n_in,
                              void* d_out, int out_size, void* d_ws, size_t ws_size,
                              hipStream_t stream) {
    const float* inp = (const float*)d_in[0];   // [256,1024,100]
    const float* wih = (const float*)d_in[1];   // [1024,2048]
    const float* whh = (const float*)d_in[2];   // [1,2048,2048]
    const float* who = (const float*)d_in[3];   // [2048,10]
    float* out = (float*)d_out;                 // [256,10]

    // ---- workspace layout ----
    unsigned char* p = (unsigned char*)d_ws;
    auto alloc = [&](size_t sz) -> void* {
        void* r = (void*)p;
        p += (sz + 255) & ~(size_t)255;
        return r;
    };
    signed char* Bq1 = (signed char*)alloc((size_t)NCH * HID * IN_DIM + 4096); // 10.5 MB
    signed char* Bq2 = (signed char*)alloc((size_t)NCH * HID * HID + 4096);    // 21 MB
    double* Who64 = (double*)alloc((size_t)HID * OUT_DIM * 8);
    ull* Xbits = (ull*)alloc((size_t)T_STEPS * B * 16 * 8);        // 3.3 MB
    ull* S1    = (ull*)alloc((size_t)T_STEPS * B * 32 * 8);        // 6.6 MB
    ull* S2    = (ull*)alloc((size_t)T_STEPS * B * 32 * 8);        // 6.6 MB
    double* v1 = (double*)alloc((size_t)B * HID * 8);
    double* v2 = (double*)alloc((size_t)B * HID * 8);
    double* vo = (double*)alloc((size_t)B * OUT_DIM * 8);
    int* cnts  = (int*)alloc((size_t)B * OUT_DIM * 4);

    size_t used = (size_t)(p - (unsigned char*)d_ws);
    size_t remain = (ws_size > used) ? (ws_size - used) : 0;
    size_t per_t = (size_t)B * HID * 8 + (size_t)B * OUT_DIM * 8 + 1024;
    int CH = (int)(remain / per_t);
    if (CH > T_STEPS) CH = T_STEPS;
    if (CH < 1) CH = 1;
    double* C3 = (double*)alloc((size_t)CH * B * OUT_DIM * 8);
    double* C  = (double*)alloc((size_t)CH * B * HID * 8);

    // ---- one-time prep ----
    cvt_w_i8<IN_DIM><<<(IN_DIM * HID + 255) / 256, 256, 0, stream>>>(wih, Bq1);
    cvt_w_i8<HID><<<(HID * HID + 255) / 256, 256, 0, stream>>>(whh, Bq2);
    cvt_who<<<(HID * OUT_DIM + 255) / 256, 256, 0, stream>>>(who, Who64);
    bitpack_input<<<(B * (IN_DIM / 64)) / 4, 256, 0, stream>>>(inp, Xbits);

    // ---- chunked time loop ----
    for (int t0 = 0; t0 < T_STEPS; t0 += CH) {
        int L = T_STEPS - t0;
        if (L > CH) L = CH;
        int rows = L * B;            // multiple of 256
        int first = (t0 == 0) ? 1 : 0;

        // layer 1
        gemm_i8<IN_DIM><<<dim3(rows / 128, HID / 32), 256, 0, stream>>>(
            Xbits, t0 * B, Bq1, C);
        lif_scan<<<(B * (HID / 64)) / 4, 256, 0, stream>>>(
            C, v1, S1, t0 * B, L, first);

        // layer 2
        gemm_i8<HID><<<dim3(rows / 128, HID / 32), 256, 0, stream>>>(
            S1, t0 * B, Bq2, C);
        lif_scan<<<(B * (HID / 64)) / 4, 256, 0, stream>>>(
            C, v2, S2, t0 * B, L, first);

        // output layer
        gemm_out<<<rows / 256, 256, 0, stream>>>(S2, t0 * B, Who64, C3);
        lif_out<<<(B * OUT_DIM + 255) / 256, 256, 0, stream>>>(
            C3, vo, cnts, out, L, first);
    }
}

// Round 13
// 2053.810 us; speedup vs baseline: 13.5814x; 1.0996x over previous
//
#include <hip/hip_runtime.h>
#include <hip/hip_bf16.h>

// SNN: B=256, IN=1024, HID=2048, OUT=10, T=100, decay=0.9, thr=1.0, reset=0.
// Layer-pipelined: GEMM1(all t) -> LIF scan -> GEMM2(all t) -> scan -> GEMM3 -> scan.
// Hidden GEMMs: i8 Ozaki split (w = 2^-39 * sum_c q_c 256^c, exact for |w|>=2^-17),
// i32 MFMA accumulation exact -> currents are exact sums (absmax 0.01025391).
// Round-13: raise occupancy 2->4 blocks/CU by shrinking LDS 54.3->36.9 KB:
//  - masks: 8-wide double-buffered window mw[2][8][128] (16 KB), restaged
//    once per 8 iters (transposed coop copy), instead of full 33.8 KB panel.
//  - B staging via __builtin_amdgcn_global_load_lds width=16 (no VGPR commit).
//  - wave tile 32r x 32c (acc [2][2][5] v4i = 80 regs), block 128r x 32c, (256,4).

#define B 256
#define IN_DIM 1024
#define HID 2048
#define OUT_DIM 10
#define T_STEPS 100
#define NCH 5

typedef unsigned long long ull;
typedef int v4i __attribute__((ext_vector_type(4)));

// ---- weight fp32 -> 5 signed base-256 digit planes of round(w*2^39),
// swizzled to MFMA-fragment order: region per (nb32, w) = 10*1024 B, fragment
// (c,ct) at offset (c*2+ct)*1024, byte lane*16+jj where lane=lk*16+li,
// n = nb32*32 + ct*16 + li, k = w*64 + lk*16 + jj. ----
template<int K>
__global__ __launch_bounds__(256) void cvt_w_i8(
    const float* __restrict__ W, signed char* __restrict__ Bq)
{
    constexpr int WPR = K / 64;
    size_t id = (size_t)blockIdx.x * 256 + threadIdx.x;
    if (id >= (size_t)K * HID) return;
    int k = (int)(id % (size_t)K);
    int n = (int)(id / (size_t)K);
    double w = (double)W[(size_t)k * HID + n];
    long long V = __double2ll_rn(w * 549755813888.0);  // w * 2^39
    int wb = k >> 6, lk = (k >> 4) & 3, jj = k & 15;
    int nb32 = n >> 5, ct = (n >> 4) & 1, li = n & 15;
    int lane = lk * 16 + li;
    size_t base = ((size_t)nb32 * WPR + wb) * 10240 + (size_t)lane * 16 + jj;
#pragma unroll
    for (int c = 0; c < 4; ++c) {
        int r = (int)(signed char)(V & 0xFF);          // balanced digit [-128,127]
        Bq[base + (size_t)(c * 2 + ct) * 1024] = (signed char)r;
        V = (V - r) >> 8;
    }
    Bq[base + (size_t)(8 + ct) * 1024] = (signed char)V;
}

// ---- output weights fp32 -> fp64 (gemm_out stays fp64) ----
__global__ __launch_bounds__(256) void cvt_who(
    const float* __restrict__ who, double* __restrict__ Who64)
{
    int i = blockIdx.x * 256 + threadIdx.x;
    if (i < HID * OUT_DIM) Who64[i] = (double)who[i];
}

// ---- bit-pack input spikes: [B, IN_DIM, T] -> Xbits[(t*256+b)*16 + i/64] ----
__global__ __launch_bounds__(256) void bitpack_input(
    const float* __restrict__ inp, ull* __restrict__ Xbits)
{
    int g = blockIdx.x * 4 + (threadIdx.x >> 6);
    int lane = threadIdx.x & 63;
    int b = g >> 4;
    int ig = g & 15;
    int i = ig * 64 + lane;
    const float* p = inp + ((size_t)b * IN_DIM + i) * T_STEPS;
    for (int t = 0; t < T_STEPS; ++t) {
        ull m = __ballot(p[t] > 0.5f);
        if (lane == 0) Xbits[((size_t)t * B + b) * 16 + ig] = m;
    }
}

// ---- i8 Ozaki bit-GEMM, LDS-staged, windowed masks + global_load_lds B ----
// Block: 128 rows x 32 cols, 4 waves (wave = 32 rows x 32 cols).
// Grid: x = rows/128, y = HID/32.
template<int K>
__global__ __launch_bounds__(256, 4) void gemm_i8(
    const ull* __restrict__ bits, int bits_row_off,
    const signed char* __restrict__ Bq, double* __restrict__ C)
{
    constexpr int WPR = K / 64;
    constexpr int NG = WPR / 8;                 // number of 8-wide mask windows
    __shared__ ull mw[2][8][128];               // 16 KB
    __shared__ __align__(16) signed char blds[2][10240];  // 20.5 KB

    const int tid = threadIdx.x;
    const int lane = tid & 63;
    const int wv = __builtin_amdgcn_readfirstlane(tid >> 6);
    const int row0 = blockIdx.x * 128;
    const int c0 = blockIdx.y * 32;
    const int li = lane & 15;
    const int lk = lane >> 4;
    const int sh = lk * 16;
    const int r0l = wv * 32;

    const ull* __restrict__ msrc = bits + (size_t)(row0 + bits_row_off) * WPR;
    const signed char* __restrict__ bsrc = Bq + (size_t)blockIdx.y * WPR * 10240;

    const int mr = tid >> 1;          // mask staging: row
    const int mw0 = (tid & 1) * 4;    // mask staging: word base within window

    // stage mask window grp into buffer mb (transposed: mw[mb][w][row])
    auto stage_masks = [&](int grp, int mb) {
        const ull* s = msrc + (size_t)mr * WPR + grp * 8 + mw0;
        ull v0 = s[0], v1 = s[1], v2 = s[2], v3 = s[3];
        mw[mb][mw0 + 0][mr] = v0;
        mw[mb][mw0 + 1][mr] = v1;
        mw[mb][mw0 + 2][mr] = v2;
        mw[mb][mw0 + 3][mr] = v3;
    };

    // stage B(w) into blds[bb] via async global->LDS (wave-uniform base + lane*16)
    auto stage_b = [&](int w, int bb) {
        const signed char* src = bsrc + (size_t)w * 10240 + lane * 16;
        int s = wv;
        __builtin_amdgcn_global_load_lds(
            (const __attribute__((address_space(1))) unsigned int*)(src + s * 1024),
            (__attribute__((address_space(3))) unsigned int*)(&blds[bb][s * 1024]), 16, 0, 0);
        s += 4;
        __builtin_amdgcn_global_load_lds(
            (const __attribute__((address_space(1))) unsigned int*)(src + s * 1024),
            (__attribute__((address_space(3))) unsigned int*)(&blds[bb][s * 1024]), 16, 0, 0);
        s += 4;
        if (s < 10)
            __builtin_amdgcn_global_load_lds(
                (const __attribute__((address_space(1))) unsigned int*)(src + s * 1024),
                (__attribute__((address_space(3))) unsigned int*)(&blds[bb][s * 1024]), 16, 0, 0);
    };

    // prologue: window 0 masks + B(w=0)
    stage_masks(0, 0);
    stage_b(0, 0);
    __syncthreads();

    v4i acc[2][2][NCH];
#pragma unroll
    for (int g = 0; g < 2; ++g)
#pragma unroll
        for (int t = 0; t < 2; ++t)
#pragma unroll
            for (int c = 0; c < NCH; ++c) acc[g][t][c] = (v4i){0, 0, 0, 0};

    int bbuf = 0, mbuf = 0;
#pragma unroll 1
    for (int w = 0; w < WPR; ++w) {
        const int wi = w & 7;
        const bool more = (w + 1 < WPR);
        if (more) stage_b(w + 1, bbuf ^ 1);
        if (wi == 0 && (w >> 3) + 1 < NG) stage_masks((w >> 3) + 1, mbuf ^ 1);

        // masks from LDS window; build A fragments (bit -> byte via mul-spread)
        ull m0 = mw[mbuf][wi][r0l + li];
        ull m1 = mw[mbuf][wi][r0l + 16 + li];
        unsigned s0 = (unsigned)(m0 >> sh) & 0xFFFFu;
        unsigned s1 = (unsigned)(m1 >> sh) & 0xFFFFu;
        v4i a0, a1;
#pragma unroll
        for (int d = 0; d < 4; ++d) {
            a0[d] = (int)((((s0 >> (4 * d)) & 0xFu) * 0x00204081u) & 0x01010101u);
            a1[d] = (int)((((s1 >> (4 * d)) & 0xFu) * 0x00204081u) & 0x01010101u);
        }

#pragma unroll
        for (int c = 0; c < NCH; ++c) {
#pragma unroll
            for (int t = 0; t < 2; ++t) {
                v4i b = *(const v4i*)(&blds[bbuf][(c * 2 + t) * 1024 + lane * 16]);
                acc[0][t][c] = __builtin_amdgcn_mfma_i32_16x16x64_i8(a0, b, acc[0][t][c], 0, 0, 0);
                acc[1][t][c] = __builtin_amdgcn_mfma_i32_16x16x64_i8(a1, b, acc[1][t][c], 0, 0, 0);
            }
        }

        __syncthreads();   // drains vmcnt (global_load_lds) + lgkmcnt (mask writes)
        bbuf ^= 1;
        if (wi == 7) mbuf ^= 1;
    }

    // exact recombination: V = ((((S4<<8)+S3)<<8+S2)<<8+S1)<<8+S0; |V| < 2^51
    // D row = row0 + r0l + g*16 + lk*4 + r
#pragma unroll
    for (int g = 0; g < 2; ++g) {
#pragma unroll
        for (int t = 0; t < 2; ++t) {
#pragma unroll
            for (int r = 0; r < 4; ++r) {
                long long V = (long long)acc[g][t][4][r];
                V = (V << 8) + (long long)acc[g][t][3][r];
                V = (V << 8) + (long long)acc[g][t][2][r];
                V = (V << 8) + (long long)acc[g][t][1][r];
                V = (V << 8) + (long long)acc[g][t][0][r];
                C[(size_t)(row0 + r0l + g * 16 + lk * 4 + r) * HID + c0 + t * 16 + li] =
                    (double)V * 0x1p-39;
            }
        }
    }
}

// ---- output bit-GEMM: 10 columns (row-lane; fp64, unchanged) ----
__global__ __launch_bounds__(256) void gemm_out(
    const ull* __restrict__ bits, int bits_row_off,
    const double* __restrict__ W, double* __restrict__ C3)
{
    const int lane = threadIdx.x & 63;
    const int wave = threadIdx.x >> 6;
    const int row = blockIdx.x * 256 + wave * 64 + lane;

    double acc[OUT_DIM];
#pragma unroll
    for (int j = 0; j < OUT_DIM; ++j) acc[j] = 0.0;

    const ull* __restrict__ brow = bits + (size_t)(row + bits_row_off) * 32;
    for (int w = 0; w < 32; ++w) {
        ull m = brow[w];
        const double* __restrict__ wk = W + (size_t)(w * 64) * OUT_DIM;
#pragma unroll 4
        for (int kk = 0; kk < 64; ++kk) {
            double bd = (double)(unsigned int)(m & 1ull);
            m >>= 1;
#pragma unroll
            for (int j = 0; j < OUT_DIM; ++j)
                acc[j] = fma(bd, wk[j], acc[j]);
            wk += OUT_DIM;
        }
    }
    double* __restrict__ crow = C3 + (size_t)row * OUT_DIM;
#pragma unroll
    for (int j = 0; j < OUT_DIM; ++j) crow[j] = acc[j];
}

// ---- LIF scan for a hidden layer (2048 units), fp64, unchanged ----
__global__ __launch_bounds__(256) void lif_scan(
    const double* __restrict__ C, double* __restrict__ vstate,
    ull* __restrict__ Sbits, int bits_row_off, int Tl, int first)
{
    int g = blockIdx.x * 4 + (threadIdx.x >> 6);
    int lane = threadIdx.x & 63;
    int b = g >> 5;
    int ng = g & 31;
    int n = ng * 64 + lane;
    double v = first ? 0.0 : vstate[(size_t)b * HID + n];
    for (int tl = 0; tl < Tl; ++tl) {
        double c = C[((size_t)tl * B + b) * HID + n];
        v = v * 0.9 + c;
        bool s = (v >= 1.0);
        if (s) v = 0.0;
        ull mask = __ballot(s);
        if (lane == 0)
            Sbits[((size_t)(bits_row_off + tl * B + b)) * 32 + ng] = mask;
    }
    vstate[(size_t)b * HID + n] = v;
}

// ---- output LIF scan + rate accumulation, unchanged ----
__global__ __launch_bounds__(256) void lif_out(
    const double* __restrict__ C3, double* __restrict__ vstate,
    int* __restrict__ cnt_state, float* __restrict__ out, int Tl, int first)
{
    int tid = blockIdx.x * 256 + threadIdx.x;
    if (tid >= B * OUT_DIM) return;
    int b = tid / OUT_DIM, o = tid % OUT_DIM;
    double v = first ? 0.0 : vstate[tid];
    int cnt = first ? 0 : cnt_state[tid];
    for (int tl = 0; tl < Tl; ++tl) {
        double c = C3[((size_t)tl * B + b) * OUT_DIM + o];
        v = v * 0.9 + c;
        if (v >= 1.0) { cnt++; v = 0.0; }
    }
    vstate[tid] = v;
    cnt_state[tid] = cnt;
    out[tid] = (float)((double)cnt / (double)T_STEPS);
}

extern "C" void kernel_launch(void* const* d_in, const int* in_sizes, int n_in,
                              void* d_out, int out_size, void* d_ws, size_t ws_size,
                              hipStream_t stream) {
    const float* inp = (const float*)d_in[0];   // [256,1024,100]
    const float* wih = (const float*)d_in[1];   // [1024,2048]
    const float* whh = (const float*)d_in[2];   // [1,2048,2048]
    const float* who = (const float*)d_in[3];   // [2048,10]
    float* out = (float*)d_out;                 // [256,10]

    // ---- workspace layout ----
    unsigned char* p = (unsigned char*)d_ws;
    auto alloc = [&](size_t sz) -> void* {
        void* r = (void*)p;
        p += (sz + 255) & ~(size_t)255;
        return r;
    };
    signed char* Bq1 = (signed char*)alloc((size_t)NCH * HID * IN_DIM + 4096); // 10.5 MB
    signed char* Bq2 = (signed char*)alloc((size_t)NCH * HID * HID + 4096);    // 21 MB
    double* Who64 = (double*)alloc((size_t)HID * OUT_DIM * 8);
    ull* Xbits = (ull*)alloc((size_t)T_STEPS * B * 16 * 8);        // 3.3 MB
    ull* S1    = (ull*)alloc((size_t)T_STEPS * B * 32 * 8);        // 6.6 MB
    ull* S2    = (ull*)alloc((size_t)T_STEPS * B * 32 * 8);        // 6.6 MB
    double* v1 = (double*)alloc((size_t)B * HID * 8);
    double* v2 = (double*)alloc((size_t)B * HID * 8);
    double* vo = (double*)alloc((size_t)B * OUT_DIM * 8);
    int* cnts  = (int*)alloc((size_t)B * OUT_DIM * 4);

    size_t used = (size_t)(p - (unsigned char*)d_ws);
    size_t remain = (ws_size > used) ? (ws_size - used) : 0;
    size_t per_t = (size_t)B * HID * 8 + (size_t)B * OUT_DIM * 8 + 1024;
    int CH = (int)(remain / per_t);
    if (CH > T_STEPS) CH = T_STEPS;
    if (CH < 1) CH = 1;
    double* C3 = (double*)alloc((size_t)CH * B * OUT_DIM * 8);
    double* C  = (double*)alloc((size_t)CH * B * HID * 8);

    // ---- one-time prep ----
    cvt_w_i8<IN_DIM><<<(IN_DIM * HID + 255) / 256, 256, 0, stream>>>(wih, Bq1);
    cvt_w_i8<HID><<<(HID * HID + 255) / 256, 256, 0, stream>>>(whh, Bq2);
    cvt_who<<<(HID * OUT_DIM + 255) / 256, 256, 0, stream>>>(who, Who64);
    bitpack_input<<<(B * (IN_DIM / 64)) / 4, 256, 0, stream>>>(inp, Xbits);

    // ---- chunked time loop ----
    for (int t0 = 0; t0 < T_STEPS; t0 += CH) {
        int L = T_STEPS - t0;
        if (L > CH) L = CH;
        int rows = L * B;            // multiple of 256
        int first = (t0 == 0) ? 1 : 0;

        // layer 1
        gemm_i8<IN_DIM><<<dim3(rows / 128, HID / 32), 256, 0, stream>>>(
            Xbits, t0 * B, Bq1, C);
        lif_scan<<<(B * (HID / 64)) / 4, 256, 0, stream>>>(
            C, v1, S1, t0 * B, L, first);

        // layer 2
        gemm_i8<HID><<<dim3(rows / 128, HID / 32), 256, 0, stream>>>(
            S1, t0 * B, Bq2, C);
        lif_scan<<<(B * (HID / 64)) / 4, 256, 0, stream>>>(
            C, v2, S2, t0 * B, L, first);

        // output layer
        gemm_out<<<rows / 256, 256, 0, stream>>>(S2, t0 * B, Who64, C3);
        lif_out<<<(B * OUT_DIM + 255) / 256, 256, 0, stream>>>(
            C3, vo, cnts, out, L, first);
    }
}

// Round 14
// 1918.568 us; speedup vs baseline: 14.5388x; 1.0705x over previous
//
#include <hip/hip_runtime.h>
#include <hip/hip_bf16.h>

// SNN: B=256, IN=1024, HID=2048, OUT=10, T=100, decay=0.9, thr=1.0, reset=0.
// Layer-pipelined: GEMM1(all t) -> LIF scan -> GEMM2(all t) -> scan -> GEMM3 -> scan.
// Hidden GEMMs: i8 Ozaki split, now 4 digit planes of round(w*2^31) (|w|max~0.55<1,
// exact split; quant err ~1e-9 rms per current). i32 MFMA accumulation exact.
// Round-14 structure (vs r13):
//  - masks TRANSPOSED in global ([w][row]) -> per-iter 2 coalesced register
//    loads with lookahead-2 ring; mask LDS window + its VALU staging deleted.
//  - B: triple-buffered LDS via global_load_lds, raw "s_waitcnt vmcnt(4);
//    s_barrier" per iter (uniform 4 VMEM issues/wave/iter, tail wraps to
//    dummy valid addresses) -> barrier never drains current-iter loads.
//  - LDS 24.6 KB; acc [2][2][4] v4i = 64 regs; (256,4).

#define B 256
#define IN_DIM 1024
#define HID 2048
#define OUT_DIM 10
#define T_STEPS 100
#define NCH 4
#define RT (T_STEPS * B)   // 25600 global rows

typedef unsigned long long ull;
typedef int v4i __attribute__((ext_vector_type(4)));

// ---- weight fp32 -> 4 signed base-256 digit planes of round(w*2^31),
// swizzled to MFMA fragment order: region per (nb32, wb) = 8192 B, fragment
// (c,ct) at (c*2+ct)*1024, byte lane*16+jj, lane=lk*16+li,
// n = nb32*32 + ct*16 + li, k = wb*64 + lk*16 + jj. ----
template<int K>
__global__ __launch_bounds__(256) void cvt_w_i8(
    const float* __restrict__ W, signed char* __restrict__ Bq)
{
    constexpr int WPR = K / 64;
    size_t id = (size_t)blockIdx.x * 256 + threadIdx.x;
    if (id >= (size_t)K * HID) return;
    int k = (int)(id % (size_t)K);
    int n = (int)(id / (size_t)K);
    double w = (double)W[(size_t)k * HID + n];
    long long V = __double2ll_rn(w * 2147483648.0);   // w * 2^31
    int wb = k >> 6, lk = (k >> 4) & 3, jj = k & 15;
    int nb32 = n >> 5, ct = (n >> 4) & 1, li = n & 15;
    int lane = lk * 16 + li;
    size_t base = ((size_t)nb32 * WPR + wb) * 8192 + (size_t)lane * 16 + jj;
#pragma unroll
    for (int c = 0; c < 3; ++c) {
        int r = (int)(signed char)(V & 0xFF);          // balanced digit [-128,127]
        Bq[base + (size_t)(c * 2 + ct) * 1024] = (signed char)r;
        V = (V - r) >> 8;
    }
    Bq[base + (size_t)(6 + ct) * 1024] = (signed char)V;  // |V| <= ~70
}

// ---- output weights fp32 -> fp64 (gemm_out stays fp64) ----
__global__ __launch_bounds__(256) void cvt_who(
    const float* __restrict__ who, double* __restrict__ Who64)
{
    int i = blockIdx.x * 256 + threadIdx.x;
    if (i < HID * OUT_DIM) Who64[i] = (double)who[i];
}

// ---- bit-pack input spikes -> TRANSPOSED XbitsT[w][t*256+b] ----
__global__ __launch_bounds__(256) void bitpack_input(
    const float* __restrict__ inp, ull* __restrict__ XbitsT)
{
    int g = blockIdx.x * 4 + (threadIdx.x >> 6);
    int lane = threadIdx.x & 63;
    int b = g >> 4;
    int ig = g & 15;
    int i = ig * 64 + lane;
    const float* p = inp + ((size_t)b * IN_DIM + i) * T_STEPS;
    for (int t = 0; t < T_STEPS; ++t) {
        ull m = __ballot(p[t] > 0.5f);
        if (lane == 0) XbitsT[(size_t)ig * RT + t * B + b] = m;
    }
}

// ---- i8 Ozaki bit-GEMM: transposed-mask register ring + triple-buffered B ----
// Block: 128 rows x 32 cols, 4 waves (wave = 32 rows x 32 cols).
// Grid: x = rows/128, y = HID/32. row_base = t0*B (global row offset).
template<int K>
__global__ __launch_bounds__(256, 4) void gemm_i8(
    const ull* __restrict__ bitsT, int row_base,
    const signed char* __restrict__ Bq, double* __restrict__ C)
{
    constexpr int WPR = K / 64;
    __shared__ __align__(16) signed char blds[3][8192];   // 24.6 KB

    const int tid = threadIdx.x;
    const int lane = tid & 63;
    const int wv = __builtin_amdgcn_readfirstlane(tid >> 6);
    const int row0 = blockIdx.x * 128;                    // local row base
    const int c0 = blockIdx.y * 32;
    const int li = lane & 15;
    const int lk = lane >> 4;
    const int sh = lk * 16;
    const int r0l = wv * 32;

    const signed char* __restrict__ bsrc = Bq + (size_t)blockIdx.y * WPR * 8192;
    const ull* __restrict__ m0p = bitsT + (row_base + row0 + r0l + li);
    const ull* __restrict__ m1p = m0p + 16;

    // stage B(w) into blds[bb]: 8 segments of 1 KB, 2 per wave (async to LDS)
    auto stage_b = [&](int w, int bb) {
        const signed char* src = bsrc + (size_t)w * 8192 + lane * 16;
        __builtin_amdgcn_global_load_lds(
            (const __attribute__((address_space(1))) unsigned int*)(src + wv * 1024),
            (__attribute__((address_space(3))) unsigned int*)(&blds[bb][wv * 1024]), 16, 0, 0);
        __builtin_amdgcn_global_load_lds(
            (const __attribute__((address_space(1))) unsigned int*)(src + (wv + 4) * 1024),
            (__attribute__((address_space(3))) unsigned int*)(&blds[bb][(wv + 4) * 1024]), 16, 0, 0);
    };

    // prologue: B(0)->buf0, B(1)->buf1; mask ring slots for w=0,1
    stage_b(0, 0);
    stage_b(1, 1);
    ull r0[2], r1[2];
    r0[0] = m0p[0];              r1[0] = m1p[0];
    r0[1] = m0p[(size_t)1 * RT]; r1[1] = m1p[(size_t)1 * RT];
    __syncthreads();

    v4i acc[2][2][NCH];
#pragma unroll
    for (int g = 0; g < 2; ++g)
#pragma unroll
        for (int t = 0; t < 2; ++t)
#pragma unroll
            for (int c = 0; c < NCH; ++c) acc[g][t][c] = (v4i){0, 0, 0, 0};

    int rb = 0, sb = 2;   // read buffer (w%3), stage buffer ((w+2)%3)
#pragma unroll 1
    for (int w = 0; w < WPR; ++w) {
        int wn = w + 2;
        if (wn >= WPR) wn -= WPR;      // tail: dummy-but-valid, never consumed
        // exactly 4 VMEM issues per wave per iter (uniform -> vmcnt(4) is exact)
        stage_b(wn, sb);
        ull m0 = r0[w & 1], m1 = r1[w & 1];
        r0[w & 1] = m0p[(size_t)wn * RT];
        r1[w & 1] = m1p[(size_t)wn * RT];

        // A fragments from masks (bit -> byte via mul-spread)
        unsigned s0 = (unsigned)(m0 >> sh) & 0xFFFFu;
        unsigned s1 = (unsigned)(m1 >> sh) & 0xFFFFu;
        v4i a0, a1;
#pragma unroll
        for (int d = 0; d < 4; ++d) {
            a0[d] = (int)((((s0 >> (4 * d)) & 0xFu) * 0x00204081u) & 0x01010101u);
            a1[d] = (int)((((s1 >> (4 * d)) & 0xFu) * 0x00204081u) & 0x01010101u);
        }

#pragma unroll
        for (int c = 0; c < NCH; ++c) {
#pragma unroll
            for (int t = 0; t < 2; ++t) {
                v4i b = *(const v4i*)(&blds[rb][(c * 2 + t) * 1024 + lane * 16]);
                acc[0][t][c] = __builtin_amdgcn_mfma_i32_16x16x64_i8(a0, b, acc[0][t][c], 0, 0, 0);
                acc[1][t][c] = __builtin_amdgcn_mfma_i32_16x16x64_i8(a1, b, acc[1][t][c], 0, 0, 0);
            }
        }

        // wait only the PREVIOUS iter's 4 loads (current 4 stay in flight)
        __asm__ __volatile__("s_waitcnt vmcnt(4)\n\ts_barrier" ::: "memory");
        rb = (rb == 2) ? 0 : rb + 1;
        sb = (sb == 2) ? 0 : sb + 1;
    }

    // exact recombination: V = (((S3<<8)+S2)<<8+S1)<<8+S0; |V| < 2^43 (double-exact)
#pragma unroll
    for (int g = 0; g < 2; ++g) {
#pragma unroll
        for (int t = 0; t < 2; ++t) {
#pragma unroll
            for (int r = 0; r < 4; ++r) {
                long long V = (long long)acc[g][t][3][r];
                V = (V << 8) + (long long)acc[g][t][2][r];
                V = (V << 8) + (long long)acc[g][t][1][r];
                V = (V << 8) + (long long)acc[g][t][0][r];
                C[(size_t)(row0 + r0l + g * 16 + lk * 4 + r) * HID + c0 + t * 16 + li] =
                    (double)V * 0x1p-31;
            }
        }
    }
}

// ---- output bit-GEMM: 10 columns, fp64; masks transposed (coalesced) ----
__global__ __launch_bounds__(256) void gemm_out(
    const ull* __restrict__ bitsT, int row_base,
    const double* __restrict__ W, double* __restrict__ C3)
{
    const int lane = threadIdx.x & 63;
    const int wave = threadIdx.x >> 6;
    const int row = blockIdx.x * 256 + wave * 64 + lane;

    double acc[OUT_DIM];
#pragma unroll
    for (int j = 0; j < OUT_DIM; ++j) acc[j] = 0.0;

    for (int w = 0; w < 32; ++w) {
        ull m = bitsT[(size_t)w * RT + row_base + row];
        const double* __restrict__ wk = W + (size_t)(w * 64) * OUT_DIM;
#pragma unroll 4
        for (int kk = 0; kk < 64; ++kk) {
            double bd = (double)(unsigned int)(m & 1ull);
            m >>= 1;
#pragma unroll
            for (int j = 0; j < OUT_DIM; ++j)
                acc[j] = fma(bd, wk[j], acc[j]);
            wk += OUT_DIM;
        }
    }
    double* __restrict__ crow = C3 + (size_t)row * OUT_DIM;
#pragma unroll
    for (int j = 0; j < OUT_DIM; ++j) crow[j] = acc[j];
}

// ---- LIF scan for a hidden layer; spike masks written TRANSPOSED ----
__global__ __launch_bounds__(256) void lif_scan(
    const double* __restrict__ C, double* __restrict__ vstate,
    ull* __restrict__ SbitsT, int row_base, int Tl, int first)
{
    int g = blockIdx.x * 4 + (threadIdx.x >> 6);
    int lane = threadIdx.x & 63;
    int b = g >> 5;
    int ng = g & 31;
    int n = ng * 64 + lane;
    double v = first ? 0.0 : vstate[(size_t)b * HID + n];
    for (int tl = 0; tl < Tl; ++tl) {
        double c = C[((size_t)tl * B + b) * HID + n];
        v = v * 0.9 + c;
        bool s = (v >= 1.0);
        if (s) v = 0.0;
        ull mask = __ballot(s);
        if (lane == 0)
            SbitsT[(size_t)ng * RT + row_base + tl * B + b] = mask;
    }
    vstate[(size_t)b * HID + n] = v;
}

// ---- output LIF scan + rate accumulation, unchanged ----
__global__ __launch_bounds__(256) void lif_out(
    const double* __restrict__ C3, double* __restrict__ vstate,
    int* __restrict__ cnt_state, float* __restrict__ out, int Tl, int first)
{
    int tid = blockIdx.x * 256 + threadIdx.x;
    if (tid >= B * OUT_DIM) return;
    int b = tid / OUT_DIM, o = tid % OUT_DIM;
    double v = first ? 0.0 : vstate[tid];
    int cnt = first ? 0 : cnt_state[tid];
    for (int tl = 0; tl < Tl; ++tl) {
        double c = C3[((size_t)tl * B + b) * OUT_DIM + o];
        v = v * 0.9 + c;
        if (v >= 1.0) { cnt++; v = 0.0; }
    }
    vstate[tid] = v;
    cnt_state[tid] = cnt;
    out[tid] = (float)((double)cnt / (double)T_STEPS);
}

extern "C" void kernel_launch(void* const* d_in, const int* in_sizes, int n_in,
                              void* d_out, int out_size, void* d_ws, size_t ws_size,
                              hipStream_t stream) {
    const float* inp = (const float*)d_in[0];   // [256,1024,100]
    const float* wih = (const float*)d_in[1];   // [1024,2048]
    const float* whh = (const float*)d_in[2];   // [1,2048,2048]
    const float* who = (const float*)d_in[3];   // [2048,10]
    float* out = (float*)d_out;                 // [256,10]

    // ---- workspace layout ----
    unsigned char* p = (unsigned char*)d_ws;
    auto alloc = [&](size_t sz) -> void* {
        void* r = (void*)p;
        p += (sz + 255) & ~(size_t)255;
        return r;
    };
    signed char* Bq1 = (signed char*)alloc((size_t)NCH * HID * IN_DIM + 4096); // 8.4 MB
    signed char* Bq2 = (signed char*)alloc((size_t)NCH * HID * HID + 4096);    // 16.8 MB
    double* Who64 = (double*)alloc((size_t)HID * OUT_DIM * 8);
    ull* XbitsT = (ull*)alloc((size_t)16 * RT * 8);        // 3.3 MB
    ull* S1T    = (ull*)alloc((size_t)32 * RT * 8);        // 6.6 MB
    ull* S2T    = (ull*)alloc((size_t)32 * RT * 8);        // 6.6 MB
    double* v1 = (double*)alloc((size_t)B * HID * 8);
    double* v2 = (double*)alloc((size_t)B * HID * 8);
    double* vo = (double*)alloc((size_t)B * OUT_DIM * 8);
    int* cnts  = (int*)alloc((size_t)B * OUT_DIM * 4);

    size_t used = (size_t)(p - (unsigned char*)d_ws);
    size_t remain = (ws_size > used) ? (ws_size - used) : 0;
    size_t per_t = (size_t)B * HID * 8 + (size_t)B * OUT_DIM * 8 + 1024;
    int CH = (int)(remain / per_t);
    if (CH > T_STEPS) CH = T_STEPS;
    if (CH < 1) CH = 1;
    double* C3 = (double*)alloc((size_t)CH * B * OUT_DIM * 8);
    double* C  = (double*)alloc((size_t)CH * B * HID * 8);

    // ---- one-time prep ----
    cvt_w_i8<IN_DIM><<<(IN_DIM * HID + 255) / 256, 256, 0, stream>>>(wih, Bq1);
    cvt_w_i8<HID><<<(HID * HID + 255) / 256, 256, 0, stream>>>(whh, Bq2);
    cvt_who<<<(HID * OUT_DIM + 255) / 256, 256, 0, stream>>>(who, Who64);
    bitpack_input<<<(B * (IN_DIM / 64)) / 4, 256, 0, stream>>>(inp, XbitsT);

    // ---- chunked time loop ----
    for (int t0 = 0; t0 < T_STEPS; t0 += CH) {
        int L = T_STEPS - t0;
        if (L > CH) L = CH;
        int rows = L * B;            // multiple of 256
        int first = (t0 == 0) ? 1 : 0;

        // layer 1
        gemm_i8<IN_DIM><<<dim3(rows / 128, HID / 32), 256, 0, stream>>>(
            XbitsT, t0 * B, Bq1, C);
        lif_scan<<<(B * (HID / 64)) / 4, 256, 0, stream>>>(
            C, v1, S1T, t0 * B, L, first);

        // layer 2
        gemm_i8<HID><<<dim3(rows / 128, HID / 32), 256, 0, stream>>>(
            S1T, t0 * B, Bq2, C);
        lif_scan<<<(B * (HID / 64)) / 4, 256, 0, stream>>>(
            C, v2, S2T, t0 * B, L, first);

        // output layer
        gemm_out<<<rows / 256, 256, 0, stream>>>(S2T, t0 * B, Who64, C3);
        lif_out<<<(B * OUT_DIM + 255) / 256, 256, 0, stream>>>(
            C3, vo, cnts, out, L, first);
    }
}